// Round 8
// baseline (133.908 us; speedup 1.0000x reference)
//
#include <hip/hip_runtime.h>

// ---------------------------------------------------------------------------
// MultiHeadAttention forward, MI355X (gfx950), bf16 MFMA pipeline.
// Round 8 = round 7 with attention re-gridded for sustained occupancy:
//   - 1024 blocks (64-row q-supertiles x 16 heads) x 4 waves, KVB=32,
//     LDS 32KB -> 4 blocks/CU co-resident (duration quadruples sum-constant)
//   - overflow check via row-sum rs (max tree removed)
//   - V LDS tile [64d][32kv] with 3-bit XOR swizzle (~2-way reads)
//   gemm/cast unchanged (round-5/6 proven).
// ---------------------------------------------------------------------------

typedef __attribute__((ext_vector_type(8))) short bf16x8;
typedef __attribute__((ext_vector_type(4))) float f32x4;
typedef __attribute__((ext_vector_type(16))) float f32x16;

#define S_LEN 4096
#define DM 1024
#define NH 16
#define DH 64

static __device__ __forceinline__ unsigned short f2bf(float f) {
  union { float f; unsigned u; } x; x.f = f;
  unsigned u = x.u;
  u += 0x7fffu + ((u >> 16) & 1u);   // round-to-nearest-even
  return (unsigned short)(u >> 16);
}

// pack two f32 -> one u32 of two bf16 (RNE), single HW instr on gfx950
static __device__ __forceinline__ unsigned pk2(float lo, float hi) {
  unsigned r;
  asm("v_cvt_pk_bf16_f32 %0, %1, %2" : "=v"(r) : "v"(lo), "v"(hi));
  return r;
}

// gfx950: element-wise half-wave exchange: vdst[32+i] <-> vsrc[i], i=0..31.
static __device__ __forceinline__ void swap32u(unsigned& a, unsigned& b) {
  asm("v_permlane32_swap_b32 %0, %1" : "+v"(a), "+v"(b));
}

static __device__ __forceinline__ float exp2_(float x) {
#if __has_builtin(__builtin_amdgcn_exp2f)
  return __builtin_amdgcn_exp2f(x);
#else
  return exp2f(x);
#endif
}

#define GLL16(gsrc, ldst)                                                      \
  __builtin_amdgcn_global_load_lds(                                            \
      (const __attribute__((address_space(1))) void*)(gsrc),                   \
      (__attribute__((address_space(3))) void*)(ldst), 16, 0, 0)

// ---------------------------------------------------------------- cast kernel
struct CastArgs {
  const float* src[8];
  unsigned short* dst[8];
  int n[8];
  float scl[8];
};

__global__ __launch_bounds__(256) void cast_all(CastArgs a) {
  int which = blockIdx.y;
  const float* __restrict__ src = a.src[which];
  unsigned short* __restrict__ dst = a.dst[which];
  int n = a.n[which];
  float s = a.scl[which];
  int i = (blockIdx.x * 256 + threadIdx.x) * 8;
  if (i >= n) return;
  f32x4 v0 = *(const f32x4*)(src + i);
  f32x4 v1 = *(const f32x4*)(src + i + 4);
  union { bf16x8 v; unsigned short u[8]; } o;
#pragma unroll
  for (int j = 0; j < 4; j++) { o.u[j] = f2bf(v0[j] * s); o.u[4 + j] = f2bf(v1[j] * s); }
  *(bf16x8*)(dst + i) = o.v;
}

// ---------------------------------------------------------------- GEMM body
// (unchanged from round 6/7 -- verified)
static __device__ __forceinline__ void gemm_body(
    const unsigned short* __restrict__ A, const unsigned short* __restrict__ B,
    void* __restrict__ Cout, int mode, unsigned short* As, unsigned short* Bs) {
  const int K = 1024;
  int tid = threadIdx.x;
  int wid = tid >> 6, lane = tid & 63;
  int m0 = blockIdx.y * 128, n0 = blockIdx.x * 128;
  int wr = (wid >> 1) * 64, wc = (wid & 1) * 64;
  int g = lane >> 4, r = lane & 15;

  const int srow = wid * 8 + (lane >> 3);
  const int scol = 8 * ((lane & 7) ^ ((lane >> 3) & 7));
  const unsigned short* gA[4];
  const unsigned short* gB[4];
#pragma unroll
  for (int rr = 0; rr < 4; rr++) {
    gA[rr] = A + (size_t)(m0 + rr * 32 + srow) * K + scol;
    gB[rr] = B + (size_t)(n0 + rr * 32 + srow) * K + scol;
  }

  f32x4 acc[4][4] = {};
  const int rsw = (r & 7) << 3;   // read-side swizzle (shorts)

  for (int k0 = 0; k0 < K; k0 += 64) {
#pragma unroll
    for (int rr = 0; rr < 4; rr++) {
      GLL16(gA[rr] + k0, As + wid * 512 + rr * 2048);
      GLL16(gB[rr] + k0, Bs + wid * 512 + rr * 2048);
    }
    __syncthreads();

#pragma unroll
    for (int kk = 0; kk < 64; kk += 32) {
      bf16x8 af[4], bfr[4];
#pragma unroll
      for (int mi = 0; mi < 4; mi++)
        af[mi] = *(const bf16x8*)&As[(wr + mi * 16 + r) * 64 + ((kk + g * 8) ^ rsw)];
#pragma unroll
      for (int ni = 0; ni < 4; ni++)
        bfr[ni] = *(const bf16x8*)&Bs[(wc + ni * 16 + r) * 64 + ((kk + g * 8) ^ rsw)];
#pragma unroll
      for (int mi = 0; mi < 4; mi++)
#pragma unroll
        for (int ni = 0; ni < 4; ni++)
          acc[mi][ni] = __builtin_amdgcn_mfma_f32_16x16x32_bf16(
              af[mi], bfr[ni], acc[mi][ni], 0, 0, 0);
    }
    __syncthreads();
  }

  if (mode == 0) {
    float* C = (float*)Cout;
#pragma unroll
    for (int mi = 0; mi < 4; mi++) {
      int row = m0 + wr + mi * 16 + g * 4;
#pragma unroll
      for (int ni = 0; ni < 4; ni++) {
        int c = n0 + wc + ni * 16 + r;
#pragma unroll
        for (int j = 0; j < 4; j++)
          C[(size_t)(row + j) * DM + c] = acc[mi][ni][j];
      }
    }
  } else if (mode == 1) {
    unsigned short* Cb = (unsigned short*)Cout;
#pragma unroll
    for (int mi = 0; mi < 4; mi++) {
      int row = m0 + wr + mi * 16 + g * 4;
#pragma unroll
      for (int ni = 0; ni < 4; ni++) {
        int c = n0 + wc + ni * 16 + r;
        int h = c >> 6, d = c & 63;
#pragma unroll
        for (int j = 0; j < 4; j++)
          Cb[(size_t)h * (S_LEN * DH) + (size_t)(row + j) * DH + d] =
              f2bf(acc[mi][ni][j]);
      }
    }
  } else {
    // V tiles: [h][s/64][d][s%64]
    unsigned short* Cb = (unsigned short*)Cout;
#pragma unroll
    for (int mi = 0; mi < 4; mi++) {
      int row = m0 + wr + mi * 16 + g * 4;
#pragma unroll
      for (int ni = 0; ni < 4; ni++) {
        int c = n0 + wc + ni * 16 + r;
        int h = c >> 6, d = c & 63;
#pragma unroll
        for (int j = 0; j < 4; j++) {
          int s = row + j;
          Cb[(size_t)h * (S_LEN * DH) + (size_t)(s >> 6) * 4096 + d * 64 + (s & 63)] =
              f2bf(acc[mi][ni][j]);
        }
      }
    }
  }
}

struct ProjArgs {
  const unsigned short* A[3];
  const unsigned short* B[3];
  unsigned short* C[3];
  int mode[3];
};

__global__ __launch_bounds__(256, 2) void gemm_proj(ProjArgs p) {
  __shared__ unsigned short As[8192];
  __shared__ unsigned short Bs[8192];
  int z = blockIdx.z;
  gemm_body(p.A[z], p.B[z], p.C[z], p.mode[z], As, Bs);
}

__global__ __launch_bounds__(256, 2) void gemm_one(
    const unsigned short* __restrict__ A, const unsigned short* __restrict__ B,
    void* __restrict__ Cout, int mode) {
  __shared__ unsigned short As[8192];
  __shared__ unsigned short Bs[8192];
  gemm_body(A, B, Cout, mode, As, Bs);
}

// ---------------------------------------------------------------- attention
// 1024 blocks (64 q-supertiles x 16 heads) x 256 threads (4 waves).
// wave = (gg = kv-half, qi = q-sub-block of 32 rows). KVB = 32 per tile.
// K: (h,s,d); V4 tiles [h][s/64][d][s%64]. LDS 32KB = [gg][db]{K 4KB,V 4KB}.
// Supertile index e mapped so co-resident quadruples have constant total work.
__global__ __launch_bounds__(256, 4) void attn_fwd(
    const unsigned short* __restrict__ Qh, const unsigned short* __restrict__ Kh,
    const unsigned short* __restrict__ V4, unsigned short* __restrict__ O) {
  __shared__ char smem[32768];   // staging; reused as combine scratch

  const int b = blockIdx.x;
  const int hd = b & 15;
  const int u = b >> 4;               // 0..63
  const int g4 = u & 15, j4 = u >> 4; // co-resident quadruple {b, b+256, ...}
  // durations (e+1): {g+1, 32-g, 33+g, 64-g} sum to 130 per CU quadruple
  const int e = (j4 == 0) ? g4 : (j4 == 1) ? (31 - g4)
              : (j4 == 2) ? (32 + g4) : (63 - g4);
  const int q0 = e * 64;
  const int nt = e + 1;               // 32-kv tiles per gg-half

  const int tid = threadIdx.x;
  const int ww = tid >> 6;
  const int gg = ww >> 1, qi = ww & 1;
  const int lane = tid & 63;
  const int l31 = lane & 31, hi = lane >> 5;
  const int qw = q0 + qi * 32;
  const int qrow = qw + l31;
  const int sw8 = (l31 & 7) << 4;                          // K read swizzle
  const int swv = (((l31 & 3) ^ ((l31 >> 2) & 3))) << 4;   // V read swizzle

  const unsigned short* Qb = Qh + (size_t)hd * (S_LEN * DH);
  const char* Kb = (const char*)(Kh + (size_t)hd * (S_LEN * DH));
  const char* Vb = (const char*)(V4 + (size_t)hd * (S_LEN * DH));

  // Q fragments (B operand): col = q (l31), k = m*16 + hi*8 + j (pre-scaled)
  bf16x8 qf[4];
#pragma unroll
  for (int m = 0; m < 4; m++)
    qf[m] = *(const bf16x8*)&Qb[(size_t)qrow * DH + m * 16 + hi * 8];

  // staging: wave (gg, qi=0) stages K (4KB), (gg, qi=1) stages V (4KB).
  // Pre-swizzled global source, linear LDS dest (4 x GLL16 = 4KB).
  int soff[4];
#pragma unroll
  for (int q2 = 0; q2 < 4; q2++) {
    if (qi == 0) {   // K: rows q2*8 + lane/8 of [32 kv][128B]
      int row = q2 * 8 + (lane >> 3);
      soff[q2] = row * 128 + (((lane & 7) * 16) ^ (((lane >> 3) & 7) << 4));
    } else {         // V: rows q2*16 + lane/4 of [64 d][half 64B within 128B row]
      int row = q2 * 16 + (lane >> 2);
      soff[q2] = row * 128 +
                 (((lane & 3) * 16) ^ ((((lane >> 2) & 3) ^ ((lane >> 4) & 3)) << 4));
    }
  }
  const int ldsc = gg * 16384 + qi * 4096;   // + db*8192

  f32x16 oacc[2] = {};    // O^T: d = dt*32 + (rg&3)+8*(rg>>2)+4*hi, col q = l31
  float m_r = 16.0f, l_r = 0.f;   // speculative-exp baseline; l_r own-half

  // prologue: stage this gg's tile 0 into db=0
  {
    const int T = gg * nt;
    const char* gp = (qi == 0) ? (Kb + (size_t)T * 4096)
                               : (Vb + (size_t)(T >> 1) * 8192 + (T & 1) * 64);
#pragma unroll
    for (int q2 = 0; q2 < 4; q2++)
      GLL16(gp + soff[q2], smem + ldsc + q2 * 1024);
  }
  __syncthreads();

  int db = 0;
  for (int it = 0; it < nt; ++it) {
    if (it + 1 < nt) {   // async prefetch next tile into alternate buffer
      const int T = gg * nt + it + 1;
      const char* gp = (qi == 0) ? (Kb + (size_t)T * 4096)
                                 : (Vb + (size_t)(T >> 1) * 8192 + (T & 1) * 64);
      char* lb = smem + gg * 16384 + (db ^ 1) * 8192 + qi * 4096;
#pragma unroll
      for (int q2 = 0; q2 < 4; q2++)
        GLL16(gp + soff[q2], lb + q2 * 1024);
    }
    const int kv0 = (gg * nt + it) * 32;
    const char* Kc = smem + gg * 16384 + db * 8192;
    const char* Vc = Kc + 4096;

    if (kv0 <= qw + 31) {                        // wave-uniform causal skip
      const bool interior = (kv0 + 31 <= qw);    // no masking anywhere
      // ---- QK^T (swapped): S^T[kv][q], log2 domain
      f32x16 s0 = {};
#pragma unroll
      for (int m = 0; m < 4; m++) {
        bf16x8 kf = *(const bf16x8*)(Kc + l31 * 128 + ((m * 32 + hi * 16) ^ sw8));
        s0 = __builtin_amdgcn_mfma_f32_32x32x16_bf16(kf, qf[m], s0, 0, 0, 0);
      }
      // ---- causal mask (diag tiles only); reg -> kv: (rg&3)+8*(rg>>2)+4*hi
      if (!interior) {
#pragma unroll
        for (int rg = 0; rg < 16; rg++) {
          const int kvl = (rg & 3) + 8 * (rg >> 2) + 4 * hi;
          s0[rg] = (kv0 + kvl <= qrow) ? s0[rg] : -1e30f;
        }
      }
      // ---- P = exp2(S - m) immediately (no max reduce on the fast path)
#pragma unroll
      for (int rg = 0; rg < 16; rg++) s0[rg] = exp2_(s0[rg] - m_r);
      // ---- own-half row-sum; doubles as the overflow sentinel (p <= rs)
      float r0 = (s0[0] + s0[1]) + (s0[2] + s0[3]);
      float r1 = (s0[4] + s0[5]) + (s0[6] + s0[7]);
      float r2 = (s0[8] + s0[9]) + (s0[10] + s0[11]);
      float r3 = (s0[12] + s0[13]) + (s0[14] + s0[15]);
      float rs = (r0 + r1) + (r2 + r3);
      if (__any(rs > 1e30f)) {     // ~never fires; exact multiplicative fixup
        float rsx = rs + __shfl_xor(rs, 32, 64);   // row-uniform across hi pair
        float sc = 1.0f / rsx;
        m_r += __log2f(rsx);
        l_r *= sc;
#pragma unroll
        for (int rg = 0; rg < 16; rg++) s0[rg] *= sc;
#pragma unroll
        for (int dt = 0; dt < 2; dt++)
#pragma unroll
          for (int rg = 0; rg < 16; rg++) oacc[dt][rg] *= sc;
        rs *= sc;
      }
      l_r += rs;
      // ---- P -> bf16 frags via cvt_pk + permlane32_swap; PV: O^T += V^T x P
#pragma unroll
      for (int n = 0; n < 2; n++) {
        unsigned a0 = pk2(s0[8 * n + 0], s0[8 * n + 1]);
        unsigned a1 = pk2(s0[8 * n + 2], s0[8 * n + 3]);
        unsigned b0 = pk2(s0[8 * n + 4], s0[8 * n + 5]);
        unsigned b1 = pk2(s0[8 * n + 6], s0[8 * n + 7]);
        swap32u(a0, b0);
        swap32u(a1, b1);
        union { unsigned w[4]; bf16x8 v; } fr;
        fr.w[0] = a0; fr.w[1] = a1; fr.w[2] = b0; fr.w[3] = b1;
#pragma unroll
        for (int dt = 0; dt < 2; dt++) {
          bf16x8 vf = *(const bf16x8*)(Vc + (dt * 32 + l31) * 64 +
                        ((n * 32 + hi * 16) ^ swv));
          oacc[dt] = __builtin_amdgcn_mfma_f32_32x32x16_bf16(
              vf, fr.v, oacc[dt], 0, 0, 0);
        }
      }
    }
    __syncthreads();
    db ^= 1;
  }

  // complete the row sum across the hi pair (one deferred shuffle)
  l_r += __shfl_xor(l_r, 32, 64);

  // ---- combine gg-halves via LDS scratch (stride 35 floats: conflict-free)
  float* scr = (float*)smem;
  const int sbase = (qi * 64 + lane) * 35;
  if (gg == 1) {
#pragma unroll
    for (int dt = 0; dt < 2; dt++)
#pragma unroll
      for (int rg = 0; rg < 16; rg++) scr[sbase + dt * 16 + rg] = oacc[dt][rg];
    scr[sbase + 32] = m_r;
    scr[sbase + 33] = l_r;
  }
  __syncthreads();
  if (gg == 0) {
    float mB = scr[sbase + 32], lB = scr[sbase + 33];
    float mS = fmaxf(m_r, mB);
    float sA = exp2_(m_r - mS);
    float sB = exp2_(mB - mS);
    float rl = 1.0f / (l_r * sA + lB * sB);
    float fA = sA * rl, fB = sB * rl;
#pragma unroll
    for (int dt = 0; dt < 2; dt++)
#pragma unroll
      for (int blk = 0; blk < 4; blk++) {
        float v0 = oacc[dt][blk * 4 + 0] * fA + scr[sbase + dt * 16 + blk * 4 + 0] * fB;
        float v1 = oacc[dt][blk * 4 + 1] * fA + scr[sbase + dt * 16 + blk * 4 + 1] * fB;
        float v2 = oacc[dt][blk * 4 + 2] * fA + scr[sbase + dt * 16 + blk * 4 + 2] * fB;
        float v3 = oacc[dt][blk * 4 + 3] * fA + scr[sbase + dt * 16 + blk * 4 + 3] * fB;
        uint2 st; st.x = pk2(v0, v1); st.y = pk2(v2, v3);
        int d0 = dt * 32 + blk * 8 + 4 * hi;
        *(uint2*)&O[(size_t)qrow * DM + hd * DH + d0] = st;
      }
  }
}

// ---------------------------------------------------------------- launch
extern "C" void kernel_launch(void* const* d_in, const int* in_sizes, int n_in,
                              void* d_out, int out_size, void* d_ws, size_t ws_size,
                              hipStream_t stream) {
  const float* q = (const float*)d_in[0];
  const float* k = (const float*)d_in[1];
  const float* v = (const float*)d_in[2];
  // d_in[3] = mask (causal, reconstructed analytically)
  const float* Wq = (const float*)d_in[4];
  const float* Wk = (const float*)d_in[5];
  const float* Wv = (const float*)d_in[6];
  const float* Wo = (const float*)d_in[7];

  unsigned short* W = (unsigned short*)d_ws;
  const int SM = S_LEN * DM;        // 4194304
  const int WM = DM * DM;           // 1048576
  unsigned short* qb  = W;
  unsigned short* kb  = qb + SM;
  unsigned short* vb  = kb + SM;
  unsigned short* Wqb = vb + SM;
  unsigned short* Wkb = Wqb + WM;
  unsigned short* Wvb = Wkb + WM;
  unsigned short* Wob = Wvb + WM;
  unsigned short* Qh  = Wob + WM;
  unsigned short* Kh  = Qh + SM;
  unsigned short* V4  = Kh + SM;
  unsigned short* Ob  = V4 + SM;

  // 1) casts; Wq carries attention scale in log2 domain: 0.125 * log2(e)
  CastArgs ca;
  ca.src[0] = q;  ca.dst[0] = qb;  ca.n[0] = SM; ca.scl[0] = 1.f;
  ca.src[1] = k;  ca.dst[1] = kb;  ca.n[1] = SM; ca.scl[1] = 1.f;
  ca.src[2] = v;  ca.dst[2] = vb;  ca.n[2] = SM; ca.scl[2] = 1.f;
  ca.src[3] = Wq; ca.dst[3] = Wqb; ca.n[3] = WM; ca.scl[3] = 0.125f * 1.44269504f;
  ca.src[4] = Wk; ca.dst[4] = Wkb; ca.n[4] = WM; ca.scl[4] = 1.f;
  ca.src[5] = Wv; ca.dst[5] = Wvb; ca.n[5] = WM; ca.scl[5] = 1.f;
  ca.src[6] = Wo; ca.dst[6] = Wob; ca.n[6] = WM; ca.scl[6] = 1.f;
  ca.src[7] = Wo; ca.dst[7] = Wob; ca.n[7] = 0;  ca.scl[7] = 1.f;
  cast_all<<<dim3(2048, 8), 256, 0, stream>>>(ca);

  // 2) batched projections: Q->(h,s,d), K->(h,s,d), V->tiles
  ProjArgs pa;
  pa.A[0] = qb; pa.B[0] = Wqb; pa.C[0] = Qh; pa.mode[0] = 1;
  pa.A[1] = kb; pa.B[1] = Wkb; pa.C[1] = Kh; pa.mode[1] = 1;
  pa.A[2] = vb; pa.B[2] = Wvb; pa.C[2] = V4; pa.mode[2] = 2;
  gemm_proj<<<dim3(8, 32, 3), 256, 0, stream>>>(pa);

  // 3) causal flash attention (64-row blocks, 4 waves, KVB=32, 4 blocks/CU)
  attn_fwd<<<dim3(1024), 256, 0, stream>>>(Qh, Kh, V4, Ob);

  // 4) output projection -> fp32
  gemm_one<<<dim3(8, 32), 256, 0, stream>>>(Ob, Wob, d_out, 0);
}